// Round 15
// baseline (14000.354 us; speedup 1.0000x reference)
//
#include <hip/hip_runtime.h>
#include <hip/hip_bf16.h>
#include <stdint.h>

// out[b,t,k,f] = sum_d x[b,t,d] * (qw[k,d,f]-qz[k,d/128,f])*sc[k,d/128,f]
// Stage 1: FRAGMENT-LINEAR bf16 panel32s in d_ws: 8KB panels (128 rows x 32 k),
//   8x1KB fragments; fragment byte l*16 = lane l's mfma_32x32x16 operand slice.
// Stage 2 (R15 = R14 + launch_bounds fix): 256x512 block, 8 waves of 128x128
//   (acc=256 VGPRs). R14 regressed 14x because __launch_bounds__(512) without
//   min-waves let the allocator cap at 128 VGPRs -> acc spilled to scratch
//   (WRITE_SIZE 40GB, VGPR_Count 128, MfmaUtil 3%). (512,1) lifts the cap;
//   LDS (96KB) limits residency to 1 block/CU regardless, same as R8.
// Schedule: R8's proven phase skeleton: 4 phases/BK-32, {GLL-stage; ds_read;
//   barrier; lgkm0; setprio; 8 MFMA; [P4: vmcnt(0)]; barrier}.

typedef __attribute__((ext_vector_type(8))) short bf16x8;
typedef __attribute__((ext_vector_type(16))) float f32x16;
typedef __attribute__((ext_vector_type(4))) float f32x4;

static constexpr int Dd = 4096, Ff = 8192;
static constexpr int M = 8192, NTOT = 16384;
static constexpr int NKT2 = Dd / 32;      // 128 K-tiles of 32
static constexpr int NMB = M / 256;       // 32 (m-blocks of 256)
static constexpr int NNB = NTOT / 512;    // 32 (n-blocks of 512)

__device__ __forceinline__ short f2bf(float f) {
    __hip_bfloat16 h = __float2bfloat16(f);
    return *reinterpret_cast<short*>(&h);
}

__device__ __forceinline__ int frag_off32(int r, int cb) {
    const int rb = r >> 5, ks = cb >> 1, kh = cb & 1;
    return ((rb * 2 + ks) << 10) + (((r & 31) + 32 * kh) << 4);
}

// ---------------- Stage 1a: x fp32 -> fragment-linear bf16 A-panel32s ----------------
__global__ __launch_bounds__(256) void xcvt(const float* __restrict__ x,
                                            char* __restrict__ Xw) {
    const int bid = blockIdx.x;             // h*128 + kt2, h in [0,64)
    const int h = bid >> 7, kt2 = bid & 127;
    const int t = threadIdx.x;
    const int r = t >> 1, seg = t & 1;
    const float* src = x + ((size_t)(h * 128 + r)) * Dd + kt2 * 32 + seg * 16;
    char* panel = Xw + ((size_t)bid << 13);
    #pragma unroll
    for (int jj = 0; jj < 2; ++jj) {
        float4 v0 = *reinterpret_cast<const float4*>(src + jj * 8);
        float4 v1 = *reinterpret_cast<const float4*>(src + jj * 8 + 4);
        union { short s[8]; bf16x8 v; } u;
        u.s[0] = f2bf(v0.x); u.s[1] = f2bf(v0.y); u.s[2] = f2bf(v0.z); u.s[3] = f2bf(v0.w);
        u.s[4] = f2bf(v1.x); u.s[5] = f2bf(v1.y); u.s[6] = f2bf(v1.z); u.s[7] = f2bf(v1.w);
        const int cb = seg * 2 + jj;
        *reinterpret_cast<bf16x8*>(panel + frag_off32(r, cb)) = u.v;
    }
}

// ---------------- Stage 1b: dequant int4 -> fragment-linear bf16 B^T panel32s ----------------
__global__ __launch_bounds__(256) void wdq(const int* __restrict__ qw,
                                           const int* __restrict__ qz,
                                           const float* __restrict__ sc,
                                           char* __restrict__ Ww) {
    const int bid = blockIdx.x;             // fh*128 + kt2, fh in [0,128)
    const int fh = bid >> 7, kt2 = bid & 127;
    const int t = threadIdx.x;
    const int r = t & 127, dh = t >> 7;
    const int n = fh * 128 + r;
    const int k = n >> 13, f = n & 8191;
    const int g = kt2 >> 2;
    const int   zv = qz[((size_t)k * 32 + g) * Ff + f];
    const float sv = sc[((size_t)k * 32 + g) * Ff + f];
    const int* qp = qw + ((size_t)(k * Dd + kt2 * 32 + dh * 16)) * Ff + f;
    char* panel = Ww + ((size_t)bid << 13);
    #pragma unroll
    for (int jj = 0; jj < 2; ++jj) {
        union { short s[8]; bf16x8 v; } u;
        #pragma unroll
        for (int e = 0; e < 8; ++e) {
            int q = qp[(size_t)(jj * 8 + e) * Ff];
            u.s[e] = f2bf((float)(q - zv) * sv);
        }
        const int cb = dh * 2 + jj;
        *reinterpret_cast<bf16x8*>(panel + frag_off32(r, cb)) = u.v;
    }
}

// ---------------- Stage 2: 256x512 block, 128x128 wave tiles ----------------
#define APAN32(H, KT2) (Xw + (((size_t)(H) * 128 + (KT2)) << 13))
#define BPAN32(H, KT2) (Ww + (((size_t)(H) * 128 + (KT2)) << 13))

#define GLL(GP, LP)                                                                \
    __builtin_amdgcn_global_load_lds(                                              \
        (const __attribute__((address_space(1))) void*)(GP),                       \
        (__attribute__((address_space(3))) void*)(LP), 16, 0, 0)

#define SB0() __builtin_amdgcn_sched_barrier(0)

// Phase (H = mb-half 0|1, KS = k-step 0|1): read frags, stage, barrier,
// lgkm-drain, 8 MFMA (2 mf x 4 nf), optional vmcnt, barrier. R8 skeleton.
#define PHASE(BUF, H, KS, LOADB, STG, WAITQ) do {                                  \
    if (LOADB) {                                                                   \
        _Pragma("unroll")                                                          \
        for (int nf = 0; nf < 4; ++nf)                                             \
            bb[nf] = *reinterpret_cast<const bf16x8*>(                             \
                (BUF) + bbase + ((nf * 2 + (KS)) << 10) + lane16);                 \
    }                                                                              \
    _Pragma("unroll")                                                              \
    for (int mf = 0; mf < 2; ++mf)                                                 \
        af[mf] = *reinterpret_cast<const bf16x8*>(                                 \
            (BUF) + abase + ((((H) * 2 + mf) * 2 + (KS)) << 10) + lane16);         \
    STG;                                                                           \
    SB0();                                                                         \
    __builtin_amdgcn_s_barrier();                                                  \
    asm volatile("s_waitcnt lgkmcnt(0)" ::: "memory");                             \
    SB0();                                                                         \
    __builtin_amdgcn_s_setprio(1);                                                 \
    _Pragma("unroll")                                                              \
    for (int mf = 0; mf < 2; ++mf)                                                 \
        _Pragma("unroll")                                                          \
        for (int nf = 0; nf < 4; ++nf)                                             \
            acc[((H) * 2 + mf) * 4 + nf] = __builtin_amdgcn_mfma_f32_32x32x16_bf16( \
                af[mf], bb[nf], acc[((H) * 2 + mf) * 4 + nf], 0, 0, 0);            \
    __builtin_amdgcn_s_setprio(0);                                                 \
    WAITQ;                                                                         \
    SB0();                                                                         \
    __builtin_amdgcn_s_barrier();                                                  \
} while (0)

#define VMD asm volatile("s_waitcnt vmcnt(0)" ::: "memory")

// one BK-32 tile T from BUF; stage tile KTN into BUFN (6 GLL over P1-P3)
#define TILE(BUF, BUFN, KTN, DOST) do {                                            \
    PHASE(BUF, 0, 0, 1,                                                            \
          { if (DOST) { GLL(APAN32(bm2,     KTN) + woff16, (BUFN) + woffu);        \
                        GLL(APAN32(bm2 + 1, KTN) + woff16, (BUFN) + 8192 + woffu); } }, ); \
    PHASE(BUF, 1, 0, 0,                                                            \
          { if (DOST) { GLL(BPAN32(bn4,     KTN) + woff16, (BUFN) + 16384 + woffu); \
                        GLL(BPAN32(bn4 + 1, KTN) + woff16, (BUFN) + 24576 + woffu); } }, ); \
    PHASE(BUF, 0, 1, 1,                                                            \
          { if (DOST) { GLL(BPAN32(bn4 + 2, KTN) + woff16, (BUFN) + 32768 + woffu); \
                        GLL(BPAN32(bn4 + 3, KTN) + woff16, (BUFN) + 40960 + woffu); } }, ); \
    PHASE(BUF, 1, 1, 0, {}, VMD);                                                  \
} while (0)

__global__ __launch_bounds__(512, 1) void gemm256(const char* __restrict__ Xw,
                                                  const char* __restrict__ Ww,
                                                  float* __restrict__ out) {
    __shared__ char lds[98304];               // 2 x 48KB (A 16KB + B 32KB)
    char* const B0 = lds;
    char* const B1 = lds + 49152;

    const int t = threadIdx.x;
    const int wave = t >> 6, lane = t & 63;
    const int wm = wave >> 2, wn = wave & 3;  // 2M x 4N waves, 128x128 each
    const int lane16 = lane << 4;

    // bijective XCD swizzle (1024 % 8 == 0); n-chunked: resident blocks
    // per XCD share one bn -> 4MB B slab ~L2-resident
    const int xcd = blockIdx.x & 7;
    const int c   = blockIdx.x >> 3;          // 0..127
    const int bn  = xcd * 4 + (c >> 5);       // 0..31
    const int bm  = c & 31;                   // 0..31
    const int bm2 = bm * 2;                   // A panels bm2, bm2+1
    const int bn4 = bn * 4;                   // B panels bn4..bn4+3

    const int woff16 = wave * 1024 + lane16;  // per-lane global offset (8KB/GLL)
    const int woffu  = wave * 1024;           // wave-uniform LDS offset
    const int abase = wm * 8192;              // wave's A panel in buffer
    const int bbase = 16384 + wn * 8192;      // wave's B panel in buffer

    bf16x8 af[2], bb[4];
    f32x16 acc[16] = {};   // [mb 0..3][nf 0..3] = 256 VGPRs

    // prologue: stage tile0 -> B0 (6 GLL); drain; barrier
    GLL(APAN32(bm2,     0) + woff16, B0 + woffu);
    GLL(APAN32(bm2 + 1, 0) + woff16, B0 + 8192 + woffu);
    GLL(BPAN32(bn4,     0) + woff16, B0 + 16384 + woffu);
    GLL(BPAN32(bn4 + 1, 0) + woff16, B0 + 24576 + woffu);
    GLL(BPAN32(bn4 + 2, 0) + woff16, B0 + 32768 + woffu);
    GLL(BPAN32(bn4 + 3, 0) + woff16, B0 + 40960 + woffu);
    VMD;
    SB0();
    __builtin_amdgcn_s_barrier();
    SB0();

    for (int i = 0; i < 64; ++i) {
        const int T = 2 * i;
        const bool nl = (i < 63);
        TILE(B0, B1, T + 1, true);
        TILE(B1, B0, T + 2, nl);
    }

    // epilogue: 32x32 C/D: col=lane&31, row=(reg&3)+8*(reg>>2)+4*(lane>>5)
    const int l31 = lane & 31;
    const int rbase = bm * 256 + wm * 128 + (lane >> 5) * 4;
    const int cbase = bn * 512 + wn * 128 + l31;
    #pragma unroll
    for (int mb = 0; mb < 4; ++mb)
        #pragma unroll
        for (int nf = 0; nf < 4; ++nf)
            #pragma unroll
            for (int reg = 0; reg < 16; ++reg) {
                const int row = rbase + mb * 32 + (reg & 3) + 8 * (reg >> 2);
                __builtin_nontemporal_store(
                    acc[mb * 4 + nf][reg],
                    &out[(size_t)row * NTOT + cbase + nf * 32]);
            }
}

// ---------------- Fallback (ws too small): round-1 fused kernel ----------------
#define LDP 72
__global__ __launch_bounds__(256) void int4_gemm(
    const float* __restrict__ x, const int* __restrict__ qw,
    const int* __restrict__ qz, const float* __restrict__ sc,
    float* __restrict__ out)
{
    __shared__ short As[128][LDP];
    __shared__ short Bs[128][LDP];
    const int t = threadIdx.x;
    int gid = (blockIdx.x & 7) * 1024 + (blockIdx.x >> 3);
    const int bm = gid & 63;
    const int bnq = gid >> 6;
    const int kse = bnq >> 6;
    const int f0  = (bnq & 63) * 128;
    const int m0  = bm * 128;
    const int wave = t >> 6, lane = t & 63;
    const int wm = wave >> 1, wn = wave & 1;
    const int l15 = lane & 15, lhi = lane >> 4;
    const int am = t >> 4, ad = (t & 15) * 4;
    const int bf = t & 127, bd = (t >> 7) * 4;
    const int*   qwk = qw + (size_t)kse * Dd * Ff;
    const int*   qzk = qz + (size_t)kse * 32 * Ff;
    const float* sck = sc + (size_t)kse * 32 * Ff;
    f32x4 acc[4][4] = {};
    for (int d0 = 0; d0 < Dd; d0 += 64) {
        __syncthreads();
        #pragma unroll
        for (int p = 0; p < 8; ++p) {
            int m = p * 16 + am;
            const float4 v = *reinterpret_cast<const float4*>(
                &x[(size_t)(m0 + m) * Dd + d0 + ad]);
            short4 wv;
            wv.x = f2bf(v.x); wv.y = f2bf(v.y); wv.z = f2bf(v.z); wv.w = f2bf(v.w);
            *reinterpret_cast<short4*>(&As[m][ad]) = wv;
        }
        {
            const int g = d0 >> 7;
            const int   zv = qzk[g * Ff + f0 + bf];
            const float sv = sck[g * Ff + f0 + bf];
            #pragma unroll
            for (int p = 0; p < 8; ++p) {
                int dl = p * 8 + bd;
                const int* qp = qwk + (size_t)(d0 + dl) * Ff + f0 + bf;
                short4 wv;
                wv.x = f2bf((float)(qp[0]      - zv) * sv);
                wv.y = f2bf((float)(qp[Ff]     - zv) * sv);
                wv.z = f2bf((float)(qp[2 * Ff] - zv) * sv);
                wv.w = f2bf((float)(qp[3 * Ff] - zv) * sv);
                *reinterpret_cast<short4*>(&Bs[bf][dl]) = wv;
            }
        }
        __syncthreads();
        #pragma unroll
        for (int kk = 0; kk < 64; kk += 32) {
            bf16x8 a2[4], b2[4];
            #pragma unroll
            for (int i = 0; i < 4; ++i)
                a2[i] = *reinterpret_cast<const bf16x8*>(&As[wm * 64 + i * 16 + l15][kk + lhi * 8]);
            #pragma unroll
            for (int i = 0; i < 4; ++i)
                b2[i] = *reinterpret_cast<const bf16x8*>(&Bs[wn * 64 + i * 16 + l15][kk + lhi * 8]);
            #pragma unroll
            for (int mi = 0; mi < 4; ++mi)
                #pragma unroll
                for (int ni = 0; ni < 4; ++ni)
                    acc[mi][ni] = __builtin_amdgcn_mfma_f32_16x16x32_bf16(
                        a2[mi], b2[ni], acc[mi][ni], 0, 0, 0);
        }
    }
    const int crow0 = m0 + wm * 64 + lhi * 4;
    const int ccol0 = bnq * 128 + wn * 64 + l15;
    #pragma unroll
    for (int mi = 0; mi < 4; ++mi)
        #pragma unroll
        for (int ni = 0; ni < 4; ++ni)
            #pragma unroll
            for (int r = 0; r < 4; ++r)
                out[(size_t)(crow0 + mi * 16 + r) * NTOT + ccol0 + ni * 16] =
                    acc[mi][ni][r];
}

extern "C" void kernel_launch(void* const* d_in, const int* in_sizes, int n_in,
                              void* d_out, int out_size, void* d_ws, size_t ws_size,
                              hipStream_t stream) {
    const float* x  = (const float*)d_in[0];
    const int*   qw = (const int*)d_in[1];
    const int*   qz = (const int*)d_in[2];
    const float* sc = (const float*)d_in[3];
    float*       out = (float*)d_out;

    const size_t xw_bytes = (size_t)(M / 128) * NKT2 * 8192;      // 64 MiB
    const size_t ww_bytes = (size_t)(NTOT / 128) * NKT2 * 8192;   // 128 MiB

    if (ws_size >= xw_bytes + ww_bytes) {
        char* Xw = (char*)d_ws;
        char* Ww = Xw + xw_bytes;
        hipLaunchKernelGGL(xcvt, dim3((M / 128) * NKT2), dim3(256), 0, stream, x, Xw);
        hipLaunchKernelGGL(wdq, dim3((NTOT / 128) * NKT2), dim3(256), 0, stream,
                           qw, qz, sc, Ww);
        hipLaunchKernelGGL(gemm256, dim3(NMB * NNB), dim3(512), 0, stream,
                           Xw, Ww, out);
    } else {
        hipLaunchKernelGGL(int4_gemm, dim3(8192), dim3(256), 0, stream,
                           x, qw, qz, sc, out);
    }
}

// Round 16
// 1405.468 us; speedup vs baseline: 9.9613x; 9.9613x over previous
//
#include <hip/hip_runtime.h>
#include <hip/hip_bf16.h>
#include <stdint.h>

// out[b,t,k,f] = sum_d x[b,t,d] * (qw[k,d,f]-qz[k,d/128,f])*sc[k,d/128,f]
// Stage 1: FRAGMENT-LINEAR bf16 panel32s in d_ws: 8KB panels (128 rows x 32 k),
//   8x1KB fragments; fragment byte l*16 = lane l's mfma_32x32x16 operand slice.
// Stage 2 (R16): m97 operating point + all accumulated wins. 128x128 block,
//   4 waves of 64x64 (acc=64 VGPRs), BK=64 SINGLE-buffered 32KB LDS,
//   __launch_bounds__(256,3) -> 3 blocks/CU. Cross-block TLP covers the
//   barrier/stage stalls that dominated every 1-block/CU config (R4-R15:
//   true MFMA occupancy ~10%, stalls ~60% of wall with nothing to overlap).
//   Plain __syncthreads(); compiler's counted-lgkm inner scheduling (m97).

typedef __attribute__((ext_vector_type(8))) short bf16x8;
typedef __attribute__((ext_vector_type(16))) float f32x16;
typedef __attribute__((ext_vector_type(4))) float f32x4;

static constexpr int Dd = 4096, Ff = 8192;
static constexpr int M = 8192, NTOT = 16384;
static constexpr int NKT2 = Dd / 32;      // 128 K-tiles of 32
static constexpr int NMB = M / 128;       // 64 (m-blocks of 128)
static constexpr int NNB = NTOT / 128;    // 128 (n-blocks of 128)

__device__ __forceinline__ short f2bf(float f) {
    __hip_bfloat16 h = __float2bfloat16(f);
    return *reinterpret_cast<short*>(&h);
}

__device__ __forceinline__ int frag_off32(int r, int cb) {
    const int rb = r >> 5, ks = cb >> 1, kh = cb & 1;
    return ((rb * 2 + ks) << 10) + (((r & 31) + 32 * kh) << 4);
}

// ---------------- Stage 1a: x fp32 -> fragment-linear bf16 A-panel32s ----------------
__global__ __launch_bounds__(256) void xcvt(const float* __restrict__ x,
                                            char* __restrict__ Xw) {
    const int bid = blockIdx.x;             // h*128 + kt2, h in [0,64)
    const int h = bid >> 7, kt2 = bid & 127;
    const int t = threadIdx.x;
    const int r = t >> 1, seg = t & 1;
    const float* src = x + ((size_t)(h * 128 + r)) * Dd + kt2 * 32 + seg * 16;
    char* panel = Xw + ((size_t)bid << 13);
    #pragma unroll
    for (int jj = 0; jj < 2; ++jj) {
        float4 v0 = *reinterpret_cast<const float4*>(src + jj * 8);
        float4 v1 = *reinterpret_cast<const float4*>(src + jj * 8 + 4);
        union { short s[8]; bf16x8 v; } u;
        u.s[0] = f2bf(v0.x); u.s[1] = f2bf(v0.y); u.s[2] = f2bf(v0.z); u.s[3] = f2bf(v0.w);
        u.s[4] = f2bf(v1.x); u.s[5] = f2bf(v1.y); u.s[6] = f2bf(v1.z); u.s[7] = f2bf(v1.w);
        const int cb = seg * 2 + jj;
        *reinterpret_cast<bf16x8*>(panel + frag_off32(r, cb)) = u.v;
    }
}

// ---------------- Stage 1b: dequant int4 -> fragment-linear bf16 B^T panel32s ----------------
__global__ __launch_bounds__(256) void wdq(const int* __restrict__ qw,
                                           const int* __restrict__ qz,
                                           const float* __restrict__ sc,
                                           char* __restrict__ Ww) {
    const int bid = blockIdx.x;             // fh*128 + kt2, fh in [0,128)
    const int fh = bid >> 7, kt2 = bid & 127;
    const int t = threadIdx.x;
    const int r = t & 127, dh = t >> 7;
    const int n = fh * 128 + r;
    const int k = n >> 13, f = n & 8191;
    const int g = kt2 >> 2;
    const int   zv = qz[((size_t)k * 32 + g) * Ff + f];
    const float sv = sc[((size_t)k * 32 + g) * Ff + f];
    const int* qp = qw + ((size_t)(k * Dd + kt2 * 32 + dh * 16)) * Ff + f;
    char* panel = Ww + ((size_t)bid << 13);
    #pragma unroll
    for (int jj = 0; jj < 2; ++jj) {
        union { short s[8]; bf16x8 v; } u;
        #pragma unroll
        for (int e = 0; e < 8; ++e) {
            int q = qp[(size_t)(jj * 8 + e) * Ff];
            u.s[e] = f2bf((float)(q - zv) * sv);
        }
        const int cb = dh * 2 + jj;
        *reinterpret_cast<bf16x8*>(panel + frag_off32(r, cb)) = u.v;
    }
}

// ---------------- Stage 2: 128x128 block, 4 waves, single-buffer, 3 blocks/CU ----------------
#define APAN32(H, KT2) (Xw + (((size_t)(H) * 128 + (KT2)) << 13))
#define BPAN32(H, KT2) (Ww + (((size_t)(H) * 128 + (KT2)) << 13))

#define GLL(GP, LP)                                                                \
    __builtin_amdgcn_global_load_lds(                                              \
        (const __attribute__((address_space(1))) void*)(GP),                       \
        (__attribute__((address_space(3))) void*)(LP), 16, 0, 0)

__global__ __launch_bounds__(256, 3) void gemm128(const char* __restrict__ Xw,
                                                  const char* __restrict__ Ww,
                                                  float* __restrict__ out) {
    __shared__ char lds[32768];   // A: 2 panel32s (16KB) | B: 2 panel32s (16KB)

    const int t = threadIdx.x;
    const int wave = t >> 6, lane = t & 63;
    const int wm = wave >> 1, wn = wave & 1;  // 2x2 waves, 64x64 each
    const int lane16 = lane << 4;

    // bijective XCD swizzle (8192 % 8 == 0); n-chunked: resident blocks per
    // XCD share 1-2 bn values -> ~1-2MB B slab L2-resident; A is L3-resident.
    const int xcd = blockIdx.x & 7;
    const int c   = blockIdx.x >> 3;          // 0..1023
    const int bn  = xcd * 16 + (c >> 6);      // 0..127
    const int bm  = c & 63;                   // 0..63

    const int woff16 = wave * 1024 + lane16;  // per-lane global offset (4KB/GLL)
    const int woffu  = wave * 1024;           // wave-uniform LDS offset

    f32x16 acc[4] = {};   // [mb 0..1][nb 0..1] = 64 VGPRs

    for (int kt = 0; kt < 64; ++kt) {
        const char* pa0 = APAN32(bm, 2 * kt);
        const char* pa1 = APAN32(bm, 2 * kt + 1);
        const char* pb0 = BPAN32(bn, 2 * kt);
        const char* pb1 = BPAN32(bn, 2 * kt + 1);
        // stage tile kt: 8 x GLL (4KB each; 256 threads x 16B)
        GLL(pa0 + woff16,        lds + woffu);
        GLL(pa0 + 4096 + woff16, lds + 4096 + woffu);
        GLL(pa1 + woff16,        lds + 8192 + woffu);
        GLL(pa1 + 4096 + woff16, lds + 12288 + woffu);
        GLL(pb0 + woff16,        lds + 16384 + woffu);
        GLL(pb0 + 4096 + woff16, lds + 20480 + woffu);
        GLL(pb1 + woff16,        lds + 24576 + woffu);
        GLL(pb1 + 4096 + woff16, lds + 28672 + woffu);
        __syncthreads();   // drains vmcnt -> tile ready

        #pragma unroll
        for (int kt2 = 0; kt2 < 2; ++kt2)
            #pragma unroll
            for (int ksl = 0; ksl < 2; ++ksl) {
                bf16x8 af[2], bb[2];
                #pragma unroll
                for (int mb = 0; mb < 2; ++mb)
                    af[mb] = *reinterpret_cast<const bf16x8*>(
                        lds + kt2 * 8192 +
                        ((((wm * 2 + mb) * 2) + ksl) << 10) + lane16);
                #pragma unroll
                for (int nb = 0; nb < 2; ++nb)
                    bb[nb] = *reinterpret_cast<const bf16x8*>(
                        lds + 16384 + kt2 * 8192 +
                        ((((wn * 2 + nb) * 2) + ksl) << 10) + lane16);
                #pragma unroll
                for (int mb = 0; mb < 2; ++mb)
                    #pragma unroll
                    for (int nb = 0; nb < 2; ++nb)
                        acc[mb * 2 + nb] = __builtin_amdgcn_mfma_f32_32x32x16_bf16(
                            af[mb], bb[nb], acc[mb * 2 + nb], 0, 0, 0);
            }
        __syncthreads();   // all reads done before next stage overwrites
    }

    // epilogue: 32x32 C/D: col=lane&31, row=(reg&3)+8*(reg>>2)+4*(lane>>5)
    const int l31 = lane & 31;
    const int rbase = bm * 128 + wm * 64 + (lane >> 5) * 4;
    const int cbase = bn * 128 + wn * 64 + l31;
    #pragma unroll
    for (int mb = 0; mb < 2; ++mb)
        #pragma unroll
        for (int nb = 0; nb < 2; ++nb)
            #pragma unroll
            for (int reg = 0; reg < 16; ++reg) {
                const int row = rbase + mb * 32 + (reg & 3) + 8 * (reg >> 2);
                __builtin_nontemporal_store(
                    acc[mb * 2 + nb][reg],
                    &out[(size_t)row * NTOT + cbase + nb * 32]);
            }
}

// ---------------- Fallback (ws too small): round-1 fused kernel ----------------
#define LDP 72
__global__ __launch_bounds__(256) void int4_gemm(
    const float* __restrict__ x, const int* __restrict__ qw,
    const int* __restrict__ qz, const float* __restrict__ sc,
    float* __restrict__ out)
{
    __shared__ short As[128][LDP];
    __shared__ short Bs[128][LDP];
    const int t = threadIdx.x;
    int gid = (blockIdx.x & 7) * 1024 + (blockIdx.x >> 3);
    const int bm = gid & 63;
    const int bnq = gid >> 6;
    const int kse = bnq >> 6;
    const int f0  = (bnq & 63) * 128;
    const int m0  = bm * 128;
    const int wave = t >> 6, lane = t & 63;
    const int wm = wave >> 1, wn = wave & 1;
    const int l15 = lane & 15, lhi = lane >> 4;
    const int am = t >> 4, ad = (t & 15) * 4;
    const int bf = t & 127, bd = (t >> 7) * 4;
    const int*   qwk = qw + (size_t)kse * Dd * Ff;
    const int*   qzk = qz + (size_t)kse * 32 * Ff;
    const float* sck = sc + (size_t)kse * 32 * Ff;
    f32x4 acc[4][4] = {};
    for (int d0 = 0; d0 < Dd; d0 += 64) {
        __syncthreads();
        #pragma unroll
        for (int p = 0; p < 8; ++p) {
            int m = p * 16 + am;
            const float4 v = *reinterpret_cast<const float4*>(
                &x[(size_t)(m0 + m) * Dd + d0 + ad]);
            short4 wv;
            wv.x = f2bf(v.x); wv.y = f2bf(v.y); wv.z = f2bf(v.z); wv.w = f2bf(v.w);
            *reinterpret_cast<short4*>(&As[m][ad]) = wv;
        }
        {
            const int g = d0 >> 7;
            const int   zv = qzk[g * Ff + f0 + bf];
            const float sv = sck[g * Ff + f0 + bf];
            #pragma unroll
            for (int p = 0; p < 8; ++p) {
                int dl = p * 8 + bd;
                const int* qp = qwk + (size_t)(d0 + dl) * Ff + f0 + bf;
                short4 wv;
                wv.x = f2bf((float)(qp[0]      - zv) * sv);
                wv.y = f2bf((float)(qp[Ff]     - zv) * sv);
                wv.z = f2bf((float)(qp[2 * Ff] - zv) * sv);
                wv.w = f2bf((float)(qp[3 * Ff] - zv) * sv);
                *reinterpret_cast<short4*>(&Bs[bf][dl]) = wv;
            }
        }
        __syncthreads();
        #pragma unroll
        for (int kk = 0; kk < 64; kk += 32) {
            bf16x8 a2[4], b2[4];
            #pragma unroll
            for (int i = 0; i < 4; ++i)
                a2[i] = *reinterpret_cast<const bf16x8*>(&As[wm * 64 + i * 16 + l15][kk + lhi * 8]);
            #pragma unroll
            for (int i = 0; i < 4; ++i)
                b2[i] = *reinterpret_cast<const bf16x8*>(&Bs[wn * 64 + i * 16 + l15][kk + lhi * 8]);
            #pragma unroll
            for (int mi = 0; mi < 4; ++mi)
                #pragma unroll
                for (int ni = 0; ni < 4; ++ni)
                    acc[mi][ni] = __builtin_amdgcn_mfma_f32_16x16x32_bf16(
                        a2[mi], b2[ni], acc[mi][ni], 0, 0, 0);
        }
    }
    const int crow0 = m0 + wm * 64 + lhi * 4;
    const int ccol0 = bnq * 128 + wn * 64 + l15;
    #pragma unroll
    for (int mi = 0; mi < 4; ++mi)
        #pragma unroll
        for (int ni = 0; ni < 4; ++ni)
            #pragma unroll
            for (int r = 0; r < 4; ++r)
                out[(size_t)(crow0 + mi * 16 + r) * NTOT + ccol0 + ni * 16] =
                    acc[mi][ni][r];
}

extern "C" void kernel_launch(void* const* d_in, const int* in_sizes, int n_in,
                              void* d_out, int out_size, void* d_ws, size_t ws_size,
                              hipStream_t stream) {
    const float* x  = (const float*)d_in[0];
    const int*   qw = (const int*)d_in[1];
    const int*   qz = (const int*)d_in[2];
    const float* sc = (const float*)d_in[3];
    float*       out = (float*)d_out;

    const size_t xw_bytes = (size_t)(M / 128) * NKT2 * 8192;      // 64 MiB
    const size_t ww_bytes = (size_t)(NTOT / 128) * NKT2 * 8192;   // 128 MiB

    if (ws_size >= xw_bytes + ww_bytes) {
        char* Xw = (char*)d_ws;
        char* Ww = Xw + xw_bytes;
        hipLaunchKernelGGL(xcvt, dim3((M / 128) * NKT2), dim3(256), 0, stream, x, Xw);
        hipLaunchKernelGGL(wdq, dim3((NTOT / 128) * NKT2), dim3(256), 0, stream,
                           qw, qz, sc, Ww);
        hipLaunchKernelGGL(gemm128, dim3(NMB * NNB), dim3(256), 0, stream,
                           Xw, Ww, out);
    } else {
        hipLaunchKernelGGL(int4_gemm, dim3(8192), dim3(256), 0, stream,
                           x, qw, qz, sc, out);
    }
}